// Round 8
// baseline (196.820 us; speedup 1.0000x reference)
//
#include <hip/hip_runtime.h>

typedef short bf16x8 __attribute__((ext_vector_type(8)));
typedef float f32x4  __attribute__((ext_vector_type(4)));

__device__ __forceinline__ unsigned short f2bf(float f) {
    unsigned int u = __float_as_uint(f);
    u += 0x7FFFu + ((u >> 16) & 1u);
    return (unsigned short)(u >> 16);
}

// tanh-form GELU: x * sigmoid(2*0.79788456*(x + 0.044715 x^3)). |err| <~5e-4 abs.
__device__ __forceinline__ float gelu_f(float x) {
    float x2 = x * x;
    float u = x * (-1.5957691216f - 0.0713548162f * x2);
    float e = __expf(u);
    return x * __builtin_amdgcn_rcpf(1.0f + e);
}

// ---------- fp32 -> bf16 elementwise ----------
__global__ void cvt_f32_bf16(const float* __restrict__ in,
                             unsigned short* __restrict__ out, int n4) {
    int stride = gridDim.x * blockDim.x;
    for (int i = blockIdx.x * blockDim.x + threadIdx.x; i < n4; i += stride) {
        float4 v = ((const float4*)in)[i];
        ushort4 r;
        r.x = f2bf(v.x); r.y = f2bf(v.y); r.z = f2bf(v.z); r.w = f2bf(v.w);
        ((ushort4*)out)[i] = r;
    }
}

// ---------- W2 [H][O] f32 -> W2T [O][H] bf16 ----------
__global__ void transpose_cvt(const float* __restrict__ in,
                              unsigned short* __restrict__ out, int H, int O) {
    __shared__ float tile[32][33];
    int o0 = blockIdx.x * 32, h0 = blockIdx.y * 32;
    int tx = threadIdx.x, ty = threadIdx.y;
    #pragma unroll
    for (int r = 0; r < 32; r += 8)
        tile[ty + r][tx] = in[(size_t)(h0 + ty + r) * O + o0 + tx];
    __syncthreads();
    #pragma unroll
    for (int r = 0; r < 32; r += 8) {
        int o = ty + r;
        out[(size_t)(o0 + o) * H + h0 + tx] = f2bf(tile[tx][o]);
    }
}

// ============ gemm1_8ph: 256x256 tile, BK=64, 8-phase counted-vmcnt ========
// C[M,N] = GELU(A[M,K]*B[N,K]^T + bias), bf16 out. 512 thr = 8 waves (2Mx4N),
// per-wave 128x64 out = acc[8][4] f32x4.
// LDS 128KB: 2 buffers x { Ak0 16K | Ak1 16K | Bk0 16K | Bk1 16K }, where
// Ak(s) = A-rows 0..255 x k-half s (32 k), 256 rows x 64B, 4 16B-slots/row.
// R7 swizzle fix: 64B rows give bank = 16*(row&1) + 4*slot, so the XOR must
// use row bits 1-2: phys_slot = logical ^ ((row>>1)&3). (R6's (row&3) XOR
// collided rows {r,r+4,r+8,r+12} -> 4-way conflict, 7.08M SQ_LDS_BANK_CONFLICT.)
// Inverse on global src (global_load_lds dest stays linear), forward on read.
// Iteration = 2 K-tiles (2t in buf0, 2t+1 in buf1), 8 phases:
//  P1 [gate] read(b0,k0,mh0)+B  stage Ak1(2t+1)->buf1   mfma q0
//  P2        read(b0,k0,mh1)    stage Bk1(2t+1)->buf1   mfma q1
//  P3 [gate] read(b0,k1,mh0)+B  stage Ak0(2t+2)->buf0   mfma q0
//  P4        read(b0,k1,mh1)    stage Bk0(2t+2)->buf0   mfma q1
//  P5 [gate] read(b1,k0,mh0)+B  stage Ak1(2t+2)->buf0   mfma q0
//  P6        read(b1,k0,mh1)    stage Bk1(2t+2)->buf0   mfma q1
//  P7 [gate] read(b1,k1,mh0)+B  stage Ak0(2t+3)->buf1   mfma q0
//  P8        read(b1,k1,mh1)    stage Bk0(2t+3)->buf1   mfma q1
// gate = s_waitcnt vmcnt(8) + s_barrier (counted: 4 half-stages = 8 loads
// always in flight; never drains to 0). Every stage targets a region whose
// last reader finished before the preceding gate barrier.
// Tail: stage kt args clamped to NTK-1; target regions are schedule-fixed,
// so clamped stages only overwrite never-again-read regions.
template <int K, int N>
__global__ __launch_bounds__(512, 2) void gemm1_8ph(
    const unsigned short* __restrict__ A,
    const unsigned short* __restrict__ B,
    const float* __restrict__ bias,
    unsigned short* __restrict__ C) {
    __shared__ __align__(16) char lds[131072];
    const int t = threadIdx.x;
    const int w = t >> 6, l = t & 63;
    constexpr int ntiles = N >> 8;

    int bid = blockIdx.x, nwg = gridDim.x;
    int wgid = ((nwg & 7) == 0) ? ((bid & 7) * (nwg >> 3) + (bid >> 3)) : bid;
    const int mt = wgid / ntiles, nt = wgid % ntiles;
    const int m0 = mt << 8, n0 = nt << 8;
    const int wr = w >> 2, wc = w & 3;

    // staging: unit u covers prow=u>>2 (0..255), phys slot u&3; logical slot
    // lg = (u&3) ^ ((prow>>1)&3) = (u&3) ^ ((u>>3)&3); global = prow*K + lg*8.
    const int u1 = t + 512;
    const int gu0 = (t >> 2) * K + (((t & 3) ^ ((t >> 3) & 3)) << 3);
    const int gu1 = (u1 >> 2) * K + (((u1 & 3) ^ ((u1 >> 3) & 3)) << 3);
    const unsigned short* Abase = A + (size_t)m0 * K;
    const unsigned short* Bbase = B + (size_t)n0 * K;

#define STAGE(PTR, KT, KS, REG) { \
    const unsigned short* g_ = (PTR) + (KT) * 64 + (KS) * 32; \
    __builtin_amdgcn_global_load_lds( \
        (const __attribute__((address_space(1))) void*)(g_ + gu0), \
        (__attribute__((address_space(3))) void*)(lds + (REG) + t * 16), 16, 0, 0); \
    __builtin_amdgcn_global_load_lds( \
        (const __attribute__((address_space(1))) void*)(g_ + gu1), \
        (__attribute__((address_space(3))) void*)(lds + (REG) + 8192 + t * 16), 16, 0, 0); }
#define PIN() { __builtin_amdgcn_sched_barrier(0); asm volatile("" ::: "memory"); }
#define GATE() { asm volatile("s_waitcnt vmcnt(8)\n\ts_barrier" ::: "memory"); \
                 __builtin_amdgcn_sched_barrier(0); }
#define LGKM() { __builtin_amdgcn_sched_barrier(0); \
                 asm volatile("s_waitcnt lgkmcnt(0)" ::: "memory"); \
                 __builtin_amdgcn_sched_barrier(0); }
#define RDB(RG) { const char* p_ = lds + (RG) + boffb; \
    bv[0] = *(const bf16x8*)(p_);        bv[1] = *(const bf16x8*)(p_ + 1024); \
    bv[2] = *(const bf16x8*)(p_ + 2048); bv[3] = *(const bf16x8*)(p_ + 3072); }
#define RDA(RG, MH) { const char* p_ = lds + (RG) + aoffb + (MH) * 4096; \
    av[0] = *(const bf16x8*)(p_);        av[1] = *(const bf16x8*)(p_ + 1024); \
    av[2] = *(const bf16x8*)(p_ + 2048); av[3] = *(const bf16x8*)(p_ + 3072); }
#define MFMA16(MB) \
    _Pragma("unroll") \
    for (int mi = 0; mi < 4; ++mi) { \
        _Pragma("unroll") \
        for (int ni = 0; ni < 4; ++ni) \
            acc[MB * 4 + mi][ni] = __builtin_amdgcn_mfma_f32_16x16x32_bf16( \
                av[mi], bv[ni], acc[MB * 4 + mi][ni], 0, 0, 0); \
    } \
    __builtin_amdgcn_s_setprio(0); \
    __builtin_amdgcn_sched_barrier(0);

    // ds_read offsets: A frag row = wr*128 + mh*64 + mi*16 + lr, slot cR=l>>4,
    // phys = cR ^ ((row>>1)&3) = cR ^ ((lr>>1)&3). B row = wc*64 + ni*16 + lr.
    const int cR = l >> 4, lr = l & 15;
    const int swz = (cR ^ ((lr >> 1) & 3)) << 4;
    const int aoffb = (wr * 128 + lr) * 64 + swz;            // + mh*4096 + mi*1024
    const int boffb = 32768 + (wc * 64 + lr) * 64 + swz;     // + ni*1024

    f32x4 acc[8][4];
    {
        f32x4 z = {0.f, 0.f, 0.f, 0.f};
        #pragma unroll
        for (int i = 0; i < 8; ++i)
            #pragma unroll
            for (int j = 0; j < 4; ++j) acc[i][j] = z;
    }
    bf16x8 av[4], bv[4];

    constexpr int NTK = K >> 6;        // K-tiles of 64
    constexpr int NT2 = K >> 7;        // main iterations (2 K-tiles each)

    // Prologue: Ak0(0),Bk0(0),Ak1(0),Bk1(0),Ak0(1),Bk0(1) — order pinned.
    STAGE(Abase, 0, 0, 0);             PIN();
    STAGE(Bbase, 0, 0, 32768);         PIN();
    STAGE(Abase, 0, 1, 16384);         PIN();
    STAGE(Bbase, 0, 1, 49152);         PIN();
    STAGE(Abase, 1, 0, 65536);         PIN();
    STAGE(Bbase, 1, 0, 98304);         PIN();

    for (int tt = 0; tt < NT2; ++tt) {
        const int k1 = (2 * tt + 1 < NTK) ? 2 * tt + 1 : NTK - 1;
        const int k2 = (2 * tt + 2 < NTK) ? 2 * tt + 2 : NTK - 1;
        const int k3 = (2 * tt + 3 < NTK) ? 2 * tt + 3 : NTK - 1;
        // P1
        GATE(); RDB(0); RDA(0, 0);
        STAGE(Abase, k1, 1, 81920);            // buf1.Ak1
        LGKM(); __builtin_amdgcn_s_setprio(1); MFMA16(0);
        // P2
        RDA(0, 1);
        STAGE(Bbase, k1, 1, 114688);           // buf1.Bk1
        LGKM(); __builtin_amdgcn_s_setprio(1); MFMA16(1);
        // P3
        GATE(); RDB(16384); RDA(16384, 0);
        STAGE(Abase, k2, 0, 0);                // buf0.Ak0
        LGKM(); __builtin_amdgcn_s_setprio(1); MFMA16(0);
        // P4
        RDA(16384, 1);
        STAGE(Bbase, k2, 0, 32768);            // buf0.Bk0
        LGKM(); __builtin_amdgcn_s_setprio(1); MFMA16(1);
        // P5
        GATE(); RDB(65536); RDA(65536, 0);
        STAGE(Abase, k2, 1, 16384);            // buf0.Ak1
        LGKM(); __builtin_amdgcn_s_setprio(1); MFMA16(0);
        // P6
        RDA(65536, 1);
        STAGE(Bbase, k2, 1, 49152);            // buf0.Bk1
        LGKM(); __builtin_amdgcn_s_setprio(1); MFMA16(1);
        // P7
        GATE(); RDB(81920); RDA(81920, 0);
        STAGE(Abase, k3, 0, 65536);            // buf1.Ak0
        LGKM(); __builtin_amdgcn_s_setprio(1); MFMA16(0);
        // P8
        RDA(81920, 1);
        STAGE(Bbase, k3, 0, 98304);            // buf1.Bk0
        LGKM(); __builtin_amdgcn_s_setprio(1); MFMA16(1);
    }
#undef STAGE
#undef PIN
#undef GATE
#undef LGKM
#undef RDB
#undef RDA
#undef MFMA16

    // Epilogue: bias + GELU -> bf16. C/D frag: col=lane&15, row=(lane>>4)*4+j.
    const int colb = n0 + wc * 64 + lr;
    float bvs[4];
    #pragma unroll
    for (int ni = 0; ni < 4; ++ni) bvs[ni] = bias[colb + ni * 16];
    #pragma unroll
    for (int mi = 0; mi < 8; ++mi)
        #pragma unroll
        for (int j = 0; j < 4; ++j) {
            size_t row = m0 + wr * 128 + mi * 16 + cR * 4 + j;
            #pragma unroll
            for (int ni = 0; ni < 4; ++ni) {
                float v = acc[mi][ni][j] + bvs[ni];
                C[row * N + colb + ni * 16] = f2bf(gelu_f(v));
            }
        }
}

// ============ gemm_k2: deep-K GEMM2 (K=3072). Tile 256x192, BK=64. =========
// 512 thr = 8 waves (2M x 4N), per-wave 128x48. LDS 2x56KB, vmcnt(7).
template <int EPI, int K, int N>
__global__ __launch_bounds__(512, 2) void gemm_k2(
    const unsigned short* __restrict__ A,
    const unsigned short* __restrict__ B,
    const float* __restrict__ bias,
    void* __restrict__ Cp) {
    constexpr int BN = 192, NREP = 3;
    constexpr int BHALF = 32768;             // A: 256 rows x 128B
    constexpr int LBUF  = BHALF + BN * 128;  // 57344
    __shared__ __align__(16) char lds[2 * LBUF];
    const int t = threadIdx.x;
    const int w = t >> 6, l = t & 63;
    constexpr int ntiles = N / BN;

    int bid = blockIdx.x;
    int nwg = gridDim.x;
    int wgid = ((nwg & 7) == 0) ? ((bid & 7) * (nwg >> 3) + (bid >> 3)) : bid;
    const int mt = wgid / ntiles, nt = wgid % ntiles;
    const int m0 = mt << 8, n0 = nt * BN;
    const int wr = w >> 2, wc = w & 3;

    const int rA = t >> 3;
    const int sl = (t & 7) ^ (rA & 7);

    auto stage = [&](int kt, char* dst) {
        const int kc = kt * 64 + sl * 8;
        #pragma unroll
        for (int i = 0; i < 4; ++i) {
            const unsigned short* ga = A + (size_t)(m0 + i * 64 + rA) * K + kc;
            char* la = dst + i * 8192 + (w << 10);
            __builtin_amdgcn_global_load_lds((const __attribute__((address_space(1))) void*)ga,
                                             (__attribute__((address_space(3))) void*)la, 16, 0, 0);
        }
        #pragma unroll
        for (int i = 0; i < NREP; ++i) {
            const unsigned short* gb = B + (size_t)(n0 + i * 64 + rA) * K + kc;
            char* lb = dst + BHALF + i * 8192 + (w << 10);
            __builtin_amdgcn_global_load_lds((const __attribute__((address_space(1))) void*)gb,
                                             (__attribute__((address_space(3))) void*)lb, 16, 0, 0);
        }
    };

    const int swz = ((l >> 4) ^ (l & 7)) << 4;
    const int aoff0 = (wr * 128 + (l & 15)) * 128 + swz;
    const int aoffX = aoff0 ^ 64;
    const int boff0 = BHALF + (wc * (BN / 4) + (l & 15)) * 128 + swz;
    const int boffX = boff0 ^ 64;

    f32x4 acc[8][NREP];
    {
        f32x4 z = {0.f, 0.f, 0.f, 0.f};
        #pragma unroll
        for (int i = 0; i < 8; ++i)
            #pragma unroll
            for (int j = 0; j < NREP; ++j) acc[i][j] = z;
    }

    constexpr int NT = K >> 6;
    stage(0, lds);
    __builtin_amdgcn_sched_barrier(0);
    asm volatile("" ::: "memory");
    stage(1, lds + LBUF);

    for (int kt = 0; kt < NT; ++kt) {
        asm volatile("s_waitcnt vmcnt(7)\n\ts_barrier" ::: "memory");
        __builtin_amdgcn_sched_barrier(0);
        const char* base = lds + (kt & 1) * LBUF;
        bf16x8 av[4][2], bv[NREP][2];
        #pragma unroll
        for (int ni = 0; ni < NREP; ++ni) {
            bv[ni][0] = *(const bf16x8*)(base + boff0 + ni * 2048);
            bv[ni][1] = *(const bf16x8*)(base + boffX + ni * 2048);
        }
        #pragma unroll
        for (int mi = 0; mi < 4; ++mi) {
            av[mi][0] = *(const bf16x8*)(base + aoff0 + mi * 2048);
            av[mi][1] = *(const bf16x8*)(base + aoffX + mi * 2048);
        }
        #pragma unroll
        for (int ksel = 0; ksel < 2; ++ksel)
            #pragma unroll
            for (int mi = 0; mi < 4; ++mi)
                #pragma unroll
                for (int ni = 0; ni < NREP; ++ni)
                    acc[mi][ni] = __builtin_amdgcn_mfma_f32_16x16x32_bf16(
                        av[mi][ksel], bv[ni][ksel], acc[mi][ni], 0, 0, 0);
        #pragma unroll
        for (int mi = 0; mi < 4; ++mi) {
            av[mi][0] = *(const bf16x8*)(base + aoff0 + (4 + mi) * 2048);
            av[mi][1] = *(const bf16x8*)(base + aoffX + (4 + mi) * 2048);
        }
        #pragma unroll
        for (int ksel = 0; ksel < 2; ++ksel)
            #pragma unroll
            for (int mi = 0; mi < 4; ++mi)
                #pragma unroll
                for (int ni = 0; ni < NREP; ++ni)
                    acc[4 + mi][ni] = __builtin_amdgcn_mfma_f32_16x16x32_bf16(
                        av[mi][ksel], bv[ni][ksel], acc[4 + mi][ni], 0, 0, 0);
        __builtin_amdgcn_sched_barrier(0);
        asm volatile("s_waitcnt lgkmcnt(0)\n\ts_barrier" ::: "memory");
        __builtin_amdgcn_sched_barrier(0);
        stage(kt + 2 < NT ? kt + 2 : NT - 1, lds + (kt & 1) * LBUF);
    }

    if constexpr (EPI == 0) {
        unsigned short* Cb = (unsigned short*)Cp;
        #pragma unroll
        for (int ni = 0; ni < NREP; ++ni) {
            int col = n0 + wc * (BN / 4) + ni * 16 + (l & 15);
            float bvs = bias[col];
            #pragma unroll
            for (int mi = 0; mi < 8; ++mi) {
                int rbase = m0 + wr * 128 + mi * 16 + ((l >> 4) << 2);
                #pragma unroll
                for (int j = 0; j < 4; ++j) {
                    float v = acc[mi][ni][j] + bvs;
                    Cb[(size_t)(rbase + j) * N + col] = f2bf(gelu_f(v));
                }
            }
        }
    } else {
        float* Cf = (float*)Cp;
        #pragma unroll
        for (int ni = 0; ni < NREP; ++ni) {
            int col = n0 + wc * (BN / 4) + ni * 16 + (l & 15);
            #pragma unroll
            for (int mi = 0; mi < 8; ++mi) {
                int rbase = m0 + wr * 128 + mi * 16 + ((l >> 4) << 2);
                #pragma unroll
                for (int j = 0; j < 4; ++j)
                    Cf[(size_t)(rbase + j) * N + col] = acc[mi][ni][j];
            }
        }
    }
}

extern "C" void kernel_launch(void* const* d_in, const int* in_sizes, int n_in,
                              void* d_out, int out_size, void* d_ws, size_t ws_size,
                              hipStream_t stream) {
    const float* x  = (const float*)d_in[0];   // [T, 768]
    const float* w1 = (const float*)d_in[1];   // [3072, 768]
    const float* b1 = (const float*)d_in[2];   // [3072]
    const float* w2 = (const float*)d_in[3];   // [3072, 768]
    float* out = (float*)d_out;                // [T, 768] fp32

    const int T = 16384, DIN = 768, DH = 3072, DOUT = 768;

    unsigned short* xb  = (unsigned short*)d_ws;            // T*DIN bf16
    unsigned short* w1b = xb  + (size_t)T * DIN;            // DH*DIN bf16 ([N][K])
    unsigned short* w2t = w1b + (size_t)DH * DIN;           // DOUT*DH bf16 ([N][K])
    unsigned short* h   = w2t + (size_t)DOUT * DH;          // CH*DH bf16

    size_t fixed = ((size_t)T * DIN + (size_t)DH * DIN + (size_t)DOUT * DH) * 2;
    int CH = T;
    while (CH > 256 && fixed + (size_t)CH * DH * 2 > ws_size) CH >>= 1;

    cvt_f32_bf16<<<2048, 256, 0, stream>>>(x, xb, T * DIN / 4);
    cvt_f32_bf16<<<1024, 256, 0, stream>>>(w1, w1b, DH * DIN / 4);
    transpose_cvt<<<dim3(DOUT / 32, DH / 32), dim3(32, 8), 0, stream>>>(w2, w2t, DH, DOUT);

    for (int c0 = 0; c0 < T; c0 += CH) {
        // h = GELU(x_chunk * W1^T + b)      M=CH, N=DH=3072, K=DIN=768
        gemm1_8ph<768, 3072><<<(CH / 256) * (DH / 256), 512, 0, stream>>>(
            xb + (size_t)c0 * DIN, w1b, b1, h);
        // out_chunk = h * W2T^T             M=CH, N=DOUT=768, K=DH=3072
        gemm_k2<1, 3072, 768><<<(CH / 256) * (DOUT / 192), 512, 0, stream>>>(
            h, w2t, b1, out + (size_t)c0 * DOUT);
    }
}

// Round 9
// 188.001 us; speedup vs baseline: 1.0469x; 1.0469x over previous
//
#include <hip/hip_runtime.h>

typedef short bf16x8 __attribute__((ext_vector_type(8)));
typedef float f32x4  __attribute__((ext_vector_type(4)));

__device__ __forceinline__ unsigned short f2bf(float f) {
    unsigned int u = __float_as_uint(f);
    u += 0x7FFFu + ((u >> 16) & 1u);
    return (unsigned short)(u >> 16);
}

// tanh-form GELU: x * sigmoid(2*0.79788456*(x + 0.044715 x^3)). |err| <~5e-4 abs.
__device__ __forceinline__ float gelu_f(float x) {
    float x2 = x * x;
    float u = x * (-1.5957691216f - 0.0713548162f * x2);
    float e = __expf(u);
    return x * __builtin_amdgcn_rcpf(1.0f + e);
}

// ---------- fp32 -> bf16 elementwise ----------
__global__ void cvt_f32_bf16(const float* __restrict__ in,
                             unsigned short* __restrict__ out, int n4) {
    int stride = gridDim.x * blockDim.x;
    for (int i = blockIdx.x * blockDim.x + threadIdx.x; i < n4; i += stride) {
        float4 v = ((const float4*)in)[i];
        ushort4 r;
        r.x = f2bf(v.x); r.y = f2bf(v.y); r.z = f2bf(v.z); r.w = f2bf(v.w);
        ((ushort4*)out)[i] = r;
    }
}

// ---------- W2 [H][O] f32 -> W2T [O][H] bf16 ----------
__global__ void transpose_cvt(const float* __restrict__ in,
                              unsigned short* __restrict__ out, int H, int O) {
    __shared__ float tile[32][33];
    int o0 = blockIdx.x * 32, h0 = blockIdx.y * 32;
    int tx = threadIdx.x, ty = threadIdx.y;
    #pragma unroll
    for (int r = 0; r < 32; r += 8)
        tile[ty + r][tx] = in[(size_t)(h0 + ty + r) * O + o0 + tx];
    __syncthreads();
    #pragma unroll
    for (int r = 0; r < 32; r += 8) {
        int o = ty + r;
        out[(size_t)(o0 + o) * H + h0 + tx] = f2bf(tile[tx][o]);
    }
}

// ============ gemm_8ph: 256xBN tile, BK=64, 8-phase counted-vmcnt ==========
// C[M,N] = epi(A[M,K]*B[N,K]^T), 512 thr = 8 waves (2M x 4N), per-wave
// 128 x BN/4 out = acc[8][NREP] f32x4 (NREP = BN/64).
// LDS 128KB: 2 bufs x { Ak0 16K | Ak1 16K | Bk0 16K | Bk1 16K }. B is ALWAYS
// staged as 256 rows (for BN=192 rows 192..255 are staged-but-never-read
// over-fetch; global reads stay inside d_ws). All regions 16KB -> staging,
// gates, and swizzle are identical for both BN (byte-for-byte = R7's proven
// schedule). 64B rows, 4 16B-slots: bank = 16*(row&1) + 4*slot, so the XOR
// uses row bits 1-2: phys_slot = logical ^ ((row>>1)&3) (R7 fix; 0 conflicts).
// Inverse on global src (global_load_lds dest stays linear), fwd on ds_read.
// Iteration = 2 K-tiles (buf0, buf1), 8 phases; gate = s_waitcnt vmcnt(8) +
// s_barrier at P1/P3/P5/P7 (counted, never 0; 12 loads in flight steady).
// Tail: stage args clamped to NTK-1; clamped stages only hit dead regions.
template <int EPI, int K, int N, int BN>
__global__ __launch_bounds__(512, 2) void gemm_8ph(
    const unsigned short* __restrict__ A,
    const unsigned short* __restrict__ B,
    const float* __restrict__ bias,
    void* __restrict__ Cp) {
    constexpr int NREP = BN / 64;
    __shared__ __align__(16) char lds[131072];
    const int t = threadIdx.x;
    const int w = t >> 6, l = t & 63;
    constexpr int ntiles = N / BN;

    int bid = blockIdx.x, nwg = gridDim.x;
    int wgid = ((nwg & 7) == 0) ? ((bid & 7) * (nwg >> 3) + (bid >> 3)) : bid;
    const int mt = wgid / ntiles, nt = wgid % ntiles;
    const int m0 = mt << 8, n0 = nt * BN;
    const int wr = w >> 2, wc = w & 3;

    // staging: unit u covers prow=u>>2 (0..255), phys slot u&3; logical slot
    // lg = (u&3) ^ ((prow>>1)&3) = (u&3) ^ ((u>>3)&3); global = prow*K + lg*8.
    const int u1 = t + 512;
    const int gu0 = (t >> 2) * K + (((t & 3) ^ ((t >> 3) & 3)) << 3);
    const int gu1 = (u1 >> 2) * K + (((u1 & 3) ^ ((u1 >> 3) & 3)) << 3);
    const unsigned short* Abase = A + (size_t)m0 * K;
    const unsigned short* Bbase = B + (size_t)n0 * K;

#define STAGE(PTR, KT, KS, REG) { \
    const unsigned short* g_ = (PTR) + (KT) * 64 + (KS) * 32; \
    __builtin_amdgcn_global_load_lds( \
        (const __attribute__((address_space(1))) void*)(g_ + gu0), \
        (__attribute__((address_space(3))) void*)(lds + (REG) + t * 16), 16, 0, 0); \
    __builtin_amdgcn_global_load_lds( \
        (const __attribute__((address_space(1))) void*)(g_ + gu1), \
        (__attribute__((address_space(3))) void*)(lds + (REG) + 8192 + t * 16), 16, 0, 0); }
#define PIN() { __builtin_amdgcn_sched_barrier(0); asm volatile("" ::: "memory"); }
#define GATE() { asm volatile("s_waitcnt vmcnt(8)\n\ts_barrier" ::: "memory"); \
                 __builtin_amdgcn_sched_barrier(0); }
#define LGKM() { __builtin_amdgcn_sched_barrier(0); \
                 asm volatile("s_waitcnt lgkmcnt(0)" ::: "memory"); \
                 __builtin_amdgcn_sched_barrier(0); }
#define RDB(RG) { const char* p_ = lds + (RG) + boffb; \
    _Pragma("unroll") \
    for (int ni_ = 0; ni_ < NREP; ++ni_) bv[ni_] = *(const bf16x8*)(p_ + ni_ * 1024); }
#define RDA(RG, MH) { const char* p_ = lds + (RG) + aoffb + (MH) * 4096; \
    av[0] = *(const bf16x8*)(p_);        av[1] = *(const bf16x8*)(p_ + 1024); \
    av[2] = *(const bf16x8*)(p_ + 2048); av[3] = *(const bf16x8*)(p_ + 3072); }
#define MFMAQ(MB) \
    _Pragma("unroll") \
    for (int mi = 0; mi < 4; ++mi) { \
        _Pragma("unroll") \
        for (int ni = 0; ni < NREP; ++ni) \
            acc[MB * 4 + mi][ni] = __builtin_amdgcn_mfma_f32_16x16x32_bf16( \
                av[mi], bv[ni], acc[MB * 4 + mi][ni], 0, 0, 0); \
    } \
    __builtin_amdgcn_s_setprio(0); \
    __builtin_amdgcn_sched_barrier(0);

    // ds_read: A frag row = wr*128 + mh*64 + mi*16 + lr, slot cR = l>>4,
    // phys = cR ^ ((row>>1)&3) = cR ^ ((lr>>1)&3). B frag row = wc*(BN/4)+ni*16+lr.
    const int cR = l >> 4, lr = l & 15;
    const int swz = (cR ^ ((lr >> 1) & 3)) << 4;
    const int aoffb = (wr * 128 + lr) * 64 + swz;              // + mh*4096 + mi*1024
    const int boffb = 32768 + (wc * (BN / 4) + lr) * 64 + swz; // + ni*1024

    f32x4 acc[8][NREP];
    {
        f32x4 z = {0.f, 0.f, 0.f, 0.f};
        #pragma unroll
        for (int i = 0; i < 8; ++i)
            #pragma unroll
            for (int j = 0; j < NREP; ++j) acc[i][j] = z;
    }
    bf16x8 av[4], bv[NREP];

    constexpr int NTK = K >> 6;        // K-tiles of 64
    constexpr int NT2 = K >> 7;        // main iterations (2 K-tiles each)

    // Prologue: Ak0(0),Bk0(0),Ak1(0),Bk1(0),Ak0(1),Bk0(1) — order pinned.
    STAGE(Abase, 0, 0, 0);             PIN();
    STAGE(Bbase, 0, 0, 32768);         PIN();
    STAGE(Abase, 0, 1, 16384);         PIN();
    STAGE(Bbase, 0, 1, 49152);         PIN();
    STAGE(Abase, 1, 0, 65536);         PIN();
    STAGE(Bbase, 1, 0, 98304);         PIN();

    for (int tt = 0; tt < NT2; ++tt) {
        const int k1 = (2 * tt + 1 < NTK) ? 2 * tt + 1 : NTK - 1;
        const int k2 = (2 * tt + 2 < NTK) ? 2 * tt + 2 : NTK - 1;
        const int k3 = (2 * tt + 3 < NTK) ? 2 * tt + 3 : NTK - 1;
        // P1
        GATE(); RDB(0); RDA(0, 0);
        STAGE(Abase, k1, 1, 81920);            // buf1.Ak1
        LGKM(); __builtin_amdgcn_s_setprio(1); MFMAQ(0);
        // P2
        RDA(0, 1);
        STAGE(Bbase, k1, 1, 114688);           // buf1.Bk1
        LGKM(); __builtin_amdgcn_s_setprio(1); MFMAQ(1);
        // P3
        GATE(); RDB(16384); RDA(16384, 0);
        STAGE(Abase, k2, 0, 0);                // buf0.Ak0
        LGKM(); __builtin_amdgcn_s_setprio(1); MFMAQ(0);
        // P4
        RDA(16384, 1);
        STAGE(Bbase, k2, 0, 32768);            // buf0.Bk0
        LGKM(); __builtin_amdgcn_s_setprio(1); MFMAQ(1);
        // P5
        GATE(); RDB(65536); RDA(65536, 0);
        STAGE(Abase, k2, 1, 16384);            // buf0.Ak1
        LGKM(); __builtin_amdgcn_s_setprio(1); MFMAQ(0);
        // P6
        RDA(65536, 1);
        STAGE(Bbase, k2, 1, 49152);            // buf0.Bk1
        LGKM(); __builtin_amdgcn_s_setprio(1); MFMAQ(1);
        // P7
        GATE(); RDB(81920); RDA(81920, 0);
        STAGE(Abase, k3, 0, 65536);            // buf1.Ak0
        LGKM(); __builtin_amdgcn_s_setprio(1); MFMAQ(0);
        // P8
        RDA(81920, 1);
        STAGE(Bbase, k3, 0, 98304);            // buf1.Bk0
        LGKM(); __builtin_amdgcn_s_setprio(1); MFMAQ(1);
    }
#undef STAGE
#undef PIN
#undef GATE
#undef LGKM
#undef RDB
#undef RDA
#undef MFMAQ

    // Epilogue. C/D frag: col = lane&15, row = (lane>>4)*4 + j  (m89-verified)
    const int colb = n0 + wc * (BN / 4) + lr;
    if constexpr (EPI == 0) {
        unsigned short* Cb = (unsigned short*)Cp;
        float bvs[NREP];
        #pragma unroll
        for (int ni = 0; ni < NREP; ++ni) bvs[ni] = bias[colb + ni * 16];
        #pragma unroll
        for (int mi = 0; mi < 8; ++mi)
            #pragma unroll
            for (int j = 0; j < 4; ++j) {
                size_t row = m0 + wr * 128 + mi * 16 + cR * 4 + j;
                #pragma unroll
                for (int ni = 0; ni < NREP; ++ni) {
                    float v = acc[mi][ni][j] + bvs[ni];
                    Cb[row * N + colb + ni * 16] = f2bf(gelu_f(v));
                }
            }
    } else {
        float* Cf = (float*)Cp;
        #pragma unroll
        for (int mi = 0; mi < 8; ++mi)
            #pragma unroll
            for (int j = 0; j < 4; ++j) {
                size_t row = m0 + wr * 128 + mi * 16 + cR * 4 + j;
                #pragma unroll
                for (int ni = 0; ni < NREP; ++ni)
                    Cf[row * N + colb + ni * 16] = acc[mi][ni][j];
            }
    }
}

extern "C" void kernel_launch(void* const* d_in, const int* in_sizes, int n_in,
                              void* d_out, int out_size, void* d_ws, size_t ws_size,
                              hipStream_t stream) {
    const float* x  = (const float*)d_in[0];   // [T, 768]
    const float* w1 = (const float*)d_in[1];   // [3072, 768]
    const float* b1 = (const float*)d_in[2];   // [3072]
    const float* w2 = (const float*)d_in[3];   // [3072, 768]
    float* out = (float*)d_out;                // [T, 768] fp32

    const int T = 16384, DIN = 768, DH = 3072, DOUT = 768;

    unsigned short* xb  = (unsigned short*)d_ws;            // T*DIN bf16
    unsigned short* w1b = xb  + (size_t)T * DIN;            // DH*DIN bf16 ([N][K])
    unsigned short* w2t = w1b + (size_t)DH * DIN;           // DOUT*DH bf16 ([N][K])
    unsigned short* h   = w2t + (size_t)DOUT * DH;          // CH*DH bf16
    // NOTE: gemm_8ph<...,192> stages 256 B-rows; for the last n-tile this
    // reads 64 rows past w2t, i.e. into h — allocated memory, never consumed.

    size_t fixed = ((size_t)T * DIN + (size_t)DH * DIN + (size_t)DOUT * DH) * 2;
    int CH = T;
    while (CH > 256 && fixed + (size_t)CH * DH * 2 > ws_size) CH >>= 1;

    cvt_f32_bf16<<<2048, 256, 0, stream>>>(x, xb, T * DIN / 4);
    cvt_f32_bf16<<<1024, 256, 0, stream>>>(w1, w1b, DH * DIN / 4);
    transpose_cvt<<<dim3(DOUT / 32, DH / 32), dim3(32, 8), 0, stream>>>(w2, w2t, DH, DOUT);

    for (int c0 = 0; c0 < T; c0 += CH) {
        // h = GELU(x_chunk * W1^T + b)      M=CH, N=DH=3072, K=DIN=768, BN=256
        gemm_8ph<0, 768, 3072, 256><<<(CH / 256) * (DH / 256), 512, 0, stream>>>(
            xb + (size_t)c0 * DIN, w1b, b1, h);
        // out_chunk = h * W2T^T             M=CH, N=DOUT=768, K=DH=3072, BN=192
        gemm_8ph<1, 3072, 768, 192><<<(CH / 256) * (DOUT / 192), 512, 0, stream>>>(
            h, w2t, b1, out + (size_t)c0 * DOUT);
    }
}